// Round 10
// baseline (1446.354 us; speedup 1.0000x reference)
//
#include <hip/hip_runtime.h>
#include <hip/hip_fp16.h>

// FixedFreqModel: B=512, L=2048, M=256, H=64, VOCAB=64, READ_FREQ=16.
// R22 = R21 (1102us steady, best) + two pure data-movement removals
// (bit-exact: identical values, only load shapes change):
//  1. kT2 -> registers: the scores k-tile is loaded once and read-only --
//     same state class as W_hh/WR (register-resident since R16). 32 uint4
//     held in regs, scores loop fully unrolled (compile-time indices).
//     Removes 32 ds_read_b128/chunk (LDS BW shared by 2 waves/CU), their
//     latency exposure, and the kT staging pass. LDS 67KB -> 34KB.
//  2. G -> float4: G4[v][j] = (a0,a1,a2,pad). Each GRU group does 4 dwordx4
//     loads instead of 12 scalar loads (16/chunk instead of 48), same
//     late-add consumption as R21.
// Everything else byte-identical to R21: KQ-fold scores, v-loop 4-acc,
// R-matvec, 4-group GRU + cndmask tokens, weights register-resident.

#define B_ 512
#define L_ 2048
#define M_ 256
#define H_ 64
#define C_ 128
#define F_ 16

typedef float v2f __attribute__((ext_vector_type(2)));
typedef _Float16 h2v __attribute__((ext_vector_type(2)));

#if __has_builtin(__builtin_amdgcn_fdot2)
__device__ __forceinline__ float FDOT2(h2v a, h2v b, float c) {
    return __builtin_amdgcn_fdot2(a, b, c, false);
}
#else
__device__ __forceinline__ float FDOT2(h2v a, h2v b, float c) {
    return c + (float)a[0]*(float)b[0] + (float)a[1]*(float)b[1];
}
#endif

__device__ __forceinline__ h2v bch(unsigned u) { return __builtin_bit_cast(h2v, u); }
__device__ __forceinline__ unsigned rl_u(unsigned v, int lane) {
    return (unsigned)__builtin_amdgcn_readlane((int)v, lane);
}
__device__ __forceinline__ float rl(float v, int lane) {
    return __int_as_float(__builtin_amdgcn_readlane(__float_as_int(v), lane));
}
__device__ __forceinline__ unsigned pkrtz(float a, float b) {
    auto r = __builtin_amdgcn_cvt_pkrtz(a, b);     // __fp16 ext_vector(2)
    return __builtin_bit_cast(unsigned, r);
}
__device__ __forceinline__ float dot4(float4 a, float4 b) {
    return a.x*b.x + a.y*b.y + a.z*b.z + a.w*b.w;
}
__device__ __forceinline__ float fast_rcp(float x) { return __builtin_amdgcn_rcpf(x); }
__device__ __forceinline__ float sigm(float x) { return fast_rcp(1.f + __expf(-x)); }
__device__ __forceinline__ float tanh_f(float x) {
    float e2 = __expf(-2.f * fabsf(x));
    return copysignf((1.f - e2) * fast_rcp(1.f + e2), x);
}
__device__ __forceinline__ unsigned h2rn(float a, float b) {
    __half2 h = __floats2half2_rn(a, b);
    return __builtin_bit_cast(unsigned, h);
}

// workspace offsets (bytes)
#define WS_KT    0u            // K'T2: 512 * 8192 u32 = 16 MB  [b][hh2][m]
#define WS_V     16777216u     // vT2: 512 * 8192 u32 = 16 MB  [b][o][mp]
#define WS_G4    33554432u     // 64*64 float4 = 64 KB  (a0,a1,a2,pad)
#define WS_WPHH  33619968u     // 6144 u32 = 24 KB  [(k2*3+g)*64+j]
#define WS_WR    33644544u     // 6144 u32 = 24 KB
#define WS_KQP   33669120u     // 1024 float4 = 16 KB (folded K.Q, packed)
#define WS_VWP   33685504u     // 16 KB
#define WS_KQF   33701888u     // 4096 fp32 = 16 KB (KQ scalar, pre-pack)
#define WS_BQ    33718272u     // 64 fp32 (bq = kb.Wq)
#define WS_KQV   33718528u     // 64 fp32 (kq = Kw^T qb)
#define WS_C0    33718784u     // 1 fp32 (c0 = kb.qb), padded
#define WS_CB    33719040u     // 512*256 fp32 = 512 KB (c[b][m])

// dynamic LDS layout (bytes)
#define S_V    0u        // 33792 : vP u32 [o=64][132] (128 mp-pairs + 4 pad)
#define S_P    33792u    // 512   : p fp16 pairs u32 [mp=128]
#define SMEM_BYTES 34304u

// ---------------- pack weights -----------------------------------------------
__global__ void pack_weights(const float* __restrict__ w_ih,
                             const float* __restrict__ w_hh,
                             const float* __restrict__ vw,
                             unsigned* __restrict__ WPhh2,
                             unsigned* __restrict__ WR2p,
                             float4* __restrict__ VWP)
{
    int idx = blockIdx.x * 256 + threadIdx.x;
    if (idx < 6144) {                        // WPhh2[(k2*3+g)*64+j]
        int j = idx & 63, t = idx >> 6, g = t % 3, k2 = t / 3;
        const float* s = w_hh + (g*64 + j)*64 + 2*k2;
        WPhh2[idx] = h2rn(s[0], s[1]);
    } else if (idx < 12288) {                // WR2p: retrieved half of w_ih
        int i = idx - 6144;
        int j = i & 63, t = i >> 6, g = t % 3, k2 = t / 3;
        const float* s = w_ih + (g*64 + j)*128 + 64 + 2*k2;
        WR2p[i] = h2rn(s[0], s[1]);
    } else if (idx < 13312) {                // VWP
        int i = idx - 12288;
        int j = i & 63, k4 = i >> 6;
        const float* s = vw + j*64 + 4*k4;
        VWP[i] = make_float4(s[0], s[1], s[2], s[3]);
    }
}

// ------ fold_kq: KQ[d][j] = sum_t Kw[t][d]*Wq[t][j]; bq, kq, c0 --------------
__global__ __launch_bounds__(64) void fold_kq(const float* __restrict__ kw,
                                              const float* __restrict__ qw,
                                              const float* __restrict__ kb,
                                              const float* __restrict__ qb,
                                              float* __restrict__ KQf,
                                              float* __restrict__ bqv,
                                              float* __restrict__ kqv,
                                              float* __restrict__ c0p)
{
    int d = blockIdx.x, j = threadIdx.x;
    __shared__ float kcol[64], kbs[64], qbs[64];
    kcol[j] = kw[j*64 + d];
    kbs[j]  = kb[j];
    qbs[j]  = qb[j];
    __syncthreads();
    float acc = 0.f, accq = 0.f;
    for (int t = 0; t < 64; ++t) {
        float kc = kcol[t];
        acc  += kc * qw[t*64 + j];
        accq += kc * qbs[t];
    }
    KQf[d*64 + j] = acc;
    if (j == 0) kqv[d] = accq;
    if (d == 0) {
        float vb = 0.f;
        for (int t = 0; t < 64; ++t) vb += kbs[t] * qw[t*64 + j];
        bqv[j] = vb;
        if (j == 0) {
            float c0 = 0.f;
            for (int t = 0; t < 64; ++t) c0 += kbs[t] * qbs[t];
            *c0p = c0;
        }
    }
}

// ------ pack_kq: KQP[k4*64+o] = (KQ[4k4+0..3][o]) for dot4 -------------------
__global__ __launch_bounds__(256) void pack_kq(const float* __restrict__ KQf,
                                               float4* __restrict__ KQP)
{
    int i = blockIdx.x * 256 + threadIdx.x;
    if (i < 1024) {
        int o = i & 63, k4 = i >> 6;
        KQP[i] = make_float4(KQf[(4*k4+0)*64 + o], KQf[(4*k4+1)*64 + o],
                             KQf[(4*k4+2)*64 + o], KQf[(4*k4+3)*64 + o]);
    }
}

// -------- G4[v][j] = (sum_k emb[v][k]*w_ih[{0,64,128}+j][k] + b, pad) --------
__global__ __launch_bounds__(64) void build_G(const float* __restrict__ embed_w,
                                              const float* __restrict__ w_ih,
                                              const float* __restrict__ b_ih,
                                              float4* __restrict__ G4)
{
    int v = blockIdx.x, j = threadIdx.x;
    __shared__ float e_s[64];
    e_s[j] = embed_w[v*64 + j];
    __syncthreads();
    float a0 = b_ih[j], a1 = b_ih[64 + j], a2 = b_ih[128 + j];
    for (int k = 0; k < 64; ++k) {
        float e = e_s[k];
        a0 += e * w_ih[j*128 + k];
        a1 += e * w_ih[(64 + j)*128 + k];
        a2 += e * w_ih[(128 + j)*128 + k];
    }
    G4[v*64 + j] = make_float4(a0, a1, a2, 0.f);
}

// ------- k/v precompute: K' (folded) pairs; v m-pair-transposed; c[b][m] -----
__global__ __launch_bounds__(256) void compute_kv(const float* __restrict__ memory,
                                                  const float* __restrict__ bqv,
                                                  const float* __restrict__ val_b,
                                                  const float4* __restrict__ KQP,
                                                  const float4* __restrict__ VWP,
                                                  const float* __restrict__ kqv,
                                                  const float* __restrict__ c0p,
                                                  unsigned* __restrict__ kT2,
                                                  unsigned* __restrict__ vT2,
                                                  float* __restrict__ cB)
{
    int wid = threadIdx.x >> 6;
    int o   = threadIdx.x & 63;
    int row = blockIdx.x * 4 + wid;          // row = b*256 + m
    int b = row >> 8, m = row & 255;
    __shared__ __align__(16) float mem_s[4][64];
    __shared__ float avs[4][64];
    mem_s[wid][o] = memory[(size_t)row * 64 + o];
    __syncthreads();
    float ak = bqv[o], av = val_b[o], ac = *c0p;
    const float4* m4  = (const float4*)mem_s[wid];
    const float4* kq4 = (const float4*)kqv;
#pragma unroll
    for (int k4 = 0; k4 < 16; ++k4) {
        float4 mm = m4[k4];
        ak += dot4(mm, KQP[k4*64 + o]);
        av += dot4(mm, VWP[k4*64 + o]);
        ac += dot4(mm, kq4[k4]);
    }
    float nb = __shfl_xor(ak, 1);            // K'[o^1][m]
    if ((o & 1) == 0)                        // pair (K'[o][m], K'[o+1][m])
        kT2[((size_t)b*32 + (o >> 1))*256 + m] = h2rn(ak, nb);
    avs[wid][o] = av;
    if (o == 0) cB[row] = ac;
    __syncthreads();
    if ((wid & 1) == 0) {                    // pair (v[m][o], v[m+1][o]), m even
        vT2[((size_t)b*64 + o)*128 + (m >> 1)] = h2rn(avs[wid][o], avs[wid+1][o]);
    }
}

// one GRU step: h broadcast as half2 via readlane; dot2 matvec; no LDS.
// G values (cg0/cg1) consumed at the TAIL so their load latency hides
// under the ~256cy matvec (fp32 reassociation only).
#define GRU_STEP(cg0, cg1, cg2) do {                                        \
    float gr = RrB, gz = RzB, gn = bhn;                                     \
    _Pragma("unroll")                                                       \
    for (int kp = 0; kp < 32; ++kp) {                                       \
        h2v hhp = bch(rl_u(hpu, 2*kp));                                     \
        gr = FDOT2(hhp, wr2[kp], gr);                                       \
        gz = FDOT2(hhp, wz2[kp], gz);                                       \
        gn = FDOT2(hhp, wn2[kp], gn);                                       \
    }                                                                       \
    float r_ = sigm(gr + (cg0));                                            \
    float z_ = sigm(gz + (cg1));                                            \
    float n_ = tanh_f(((cg2) + Rn) + r_ * gn);                              \
    h = fmaf(z_, h - n_, n_);                                               \
    float hx_ = __shfl_xor(h, 1);                                           \
    hpu = pkrtz(h, hx_);                                                    \
} while (0)

// ---------------- main recurrent kernel: 1 wave per batch element ------------
__global__ __launch_bounds__(64, 1) void recurrent_main(
    const int*   __restrict__ seq,
    const float* __restrict__ b_hh,
    const float* __restrict__ head_w,
    const float* __restrict__ head_b,
    const unsigned* __restrict__ kT2g,
    const unsigned* __restrict__ vT2g,
    const float4* __restrict__ G4,
    const unsigned* __restrict__ WPhh2,
    const unsigned* __restrict__ WR2p,
    const float* __restrict__ cB,
    float* __restrict__ out)
{
    const int b = blockIdx.x;
    const int j = threadIdx.x;

    extern __shared__ __align__(16) char smem[];

    // ---- stage vT2 (repad 128->132 u32 rows) into LDS once ----
    {
        const uint4* vg4 = (const uint4*)(vT2g + (size_t)b * 8192);
        uint4* vls4 = (uint4*)(smem + S_V);
#pragma unroll
        for (int i = 0; i < 32; ++i) {
            int t = i*64 + j;                 // global quad: o = t>>5, q = t&31
            vls4[(t >> 5)*33 + (t & 31)] = vg4[t];
        }
    }

    // ---- kT column for lane j: 32 uint4, read-only, register-resident
    //      (same class as the weight tables below) ----
    uint4 kk[32];
    {
        const uint4* kTg = (const uint4*)(kT2g + (size_t)b * 8192);
#pragma unroll
        for (int t = 0; t < 32; ++t) kk[t] = kTg[t*64 + j];
    }

    // ---- W_hh in registers as half2: 96 words (compiler parks in AGPRs) ----
    h2v wr2[32], wz2[32], wn2[32];
#pragma unroll
    for (int k2 = 0; k2 < 32; ++k2) {
        wr2[k2] = bch(WPhh2[(k2*3 + 0)*64 + j]);
        wz2[k2] = bch(WPhh2[(k2*3 + 1)*64 + j]);
        wn2[k2] = bch(WPhh2[(k2*3 + 2)*64 + j]);
    }
    // ---- WR (retrieved-half of w_ih) likewise: 96 words, loaded ONCE ----
    h2v rr2[32], rz2[32], rn2[32];
#pragma unroll
    for (int k2 = 0; k2 < 32; ++k2) {
        rr2[k2] = bch(WR2p[(k2*3 + 0)*64 + j]);
        rz2[k2] = bch(WR2p[(k2*3 + 1)*64 + j]);
        rn2[k2] = bch(WR2p[(k2*3 + 2)*64 + j]);
    }

    float h = 0.f;                       // lane j owns h[j]; never leaves regs
    unsigned hpu = 0u;                   // packed (h[2t], h[2t+1]) fp16 pair
    const float bhr = b_hh[j], bhz = b_hh[64 + j], bhn = b_hh[128 + j];
    // scores bias: c[b][m] for lane's m = 4j..4j+3 (fp32, in regs all session)
    const float4 cc = *(const float4*)(cB + (size_t)b*256 + 4*j);

    const int* seqb = seq + (size_t)b * L_;
    const uint4* vrow = (const uint4*)(smem + S_V) + j*33;   // lane's o-row
    const uint4* p4   = (const uint4*)(smem + S_P);
    __builtin_amdgcn_wave_barrier();

    for (int c = 0; c < C_; ++c) {
        const int c16 = c * F_;

        // ---- token hoist: all 4 group int4s issued at chunk top ----
        const int4 pA = *(const int4*)(seqb + c16);
        const int4 pB = *(const int4*)(seqb + c16 + 4);
        const int4 pC = *(const int4*)(seqb + c16 + 8);
        const int4 pD = *(const int4*)(seqb + c16 + 12);

        // ---- scores from h pairs, k-tile in regs: lane j owns m=4j..4j+3 ----
        float s0 = cc.x, s1 = cc.y, s2 = cc.z, s3 = cc.w;
#pragma unroll
        for (int t = 0; t < 32; ++t) {
            h2v qq = bch(rl_u(hpu, 2*t));
            s0 = FDOT2(bch(kk[t].x), qq, s0);
            s1 = FDOT2(bch(kk[t].y), qq, s1);
            s2 = FDOT2(bch(kk[t].z), qq, s2);
            s3 = FDOT2(bch(kk[t].w), qq, s3);
        }
        const float scale = 0.125f;
        // softmax, no max-sub (|s| small), rcp not div
        float4 p;
        p.x = __expf(s0*scale); p.y = __expf(s1*scale);
        p.z = __expf(s2*scale); p.w = __expf(s3*scale);
        float sum = (p.x + p.y) + (p.z + p.w);
#pragma unroll
        for (int o = 32; o > 0; o >>= 1) sum += __shfl_xor(sum, o);
        float inv = fast_rcp(sum);
        // p as fp16 pairs (unnormalized): mp=2j -> (p[4j],p[4j+1]); 2j+1 -> ...
        *(uint2*)(smem + S_P + (size_t)j*8) =
            make_uint2(pkrtz(p.x, p.y), pkrtz(p.z, p.w));
        __builtin_amdgcn_wave_barrier();

        // ---- retrieved: lane j owns ret[j]; 4 accs (chain depth 32) ----
        float r0 = 0.f, r1 = 0.f, r2 = 0.f, r3 = 0.f;
#pragma unroll 8
        for (int qd = 0; qd < 32; ++qd) {
            uint4 vv = vrow[qd];          // pairs mp = 4qd..4qd+3 for o=j
            uint4 pp = p4[qd];            // broadcast
            r0 = FDOT2(bch(pp.x), bch(vv.x), r0);
            r1 = FDOT2(bch(pp.y), bch(vv.y), r1);
            r2 = FDOT2(bch(pp.z), bch(vv.z), r2);
            r3 = FDOT2(bch(pp.w), bch(vv.w), r3);
        }
        float ret = ((r0 + r1) + (r2 + r3)) * inv;

        // ---- R matvec: ret packed like h (pairs via shfl); WR in regs ----
        float rx = __shfl_xor(ret, 1);
        unsigned rpu = pkrtz(ret, rx);
        float Rr = 0.f, Rz = 0.f, Rn = 0.f;
#pragma unroll
        for (int k2 = 0; k2 < 32; ++k2) {
            h2v rr = bch(rl_u(rpu, 2*k2));
            Rr = FDOT2(rr, rr2[k2], Rr);
            Rz = FDOT2(rr, rz2[k2], Rz);
            Rn = FDOT2(rr, rn2[k2], Rn);
        }
        const float RrB = Rr + bhr, RzB = Rz + bhz;

        // ---- 16 GRU steps: 4 dynamic groups x 4 unrolled (I-cache OK).
        //      Tokens from hoisted regs via cndmask; G4 dwordx4 loads issued
        //      at group top, consumed at step tails (late-add). ----
#pragma unroll 1
        for (int g = 0; g < 4; ++g) {
            const bool gb1 = (g & 1), gb2 = (g & 2);
            int4 tlo, thi, tg;
            tlo.x = gb1 ? pB.x : pA.x; tlo.y = gb1 ? pB.y : pA.y;
            tlo.z = gb1 ? pB.z : pA.z; tlo.w = gb1 ? pB.w : pA.w;
            thi.x = gb1 ? pD.x : pC.x; thi.y = gb1 ? pD.y : pC.y;
            thi.z = gb1 ? pD.z : pC.z; thi.w = gb1 ? pD.w : pC.w;
            tg.x = gb2 ? thi.x : tlo.x; tg.y = gb2 ? thi.y : tlo.y;
            tg.z = gb2 ? thi.z : tlo.z; tg.w = gb2 ? thi.w : tlo.w;
            const float4 gA = G4[tg.x*64 + j];
            const float4 gB = G4[tg.y*64 + j];
            const float4 gC = G4[tg.z*64 + j];
            const float4 gD = G4[tg.w*64 + j];

            GRU_STEP(gA.x, gA.y, gA.z);
            GRU_STEP(gB.x, gB.y, gB.z);
            GRU_STEP(gC.x, gC.y, gC.z);
            GRU_STEP(gD.x, gD.y, gD.z);
        }
    }

    // ---- head: out[b][j] = head_b[j] + sum_k h[k]*head_w[j][k] (fp32) ----
    float o = head_b[j];
#pragma unroll
    for (int k4 = 0; k4 < 16; ++k4) {
        float h0 = rl(h, 4*k4+0), h1 = rl(h, 4*k4+1);
        float h2 = rl(h, 4*k4+2), h3 = rl(h, 4*k4+3);
        const float* hw = head_w + j*64 + 4*k4;
        o += h0*hw[0] + h1*hw[1] + h2*hw[2] + h3*hw[3];
    }
    out[(size_t)b*64 + j] = o;
}

extern "C" void kernel_launch(void* const* d_in, const int* in_sizes, int n_in,
                              void* d_out, int out_size, void* d_ws, size_t ws_size,
                              hipStream_t stream) {
    const int*   seq      = (const int*)  d_in[0];
    const float* memory   = (const float*)d_in[1];
    const float* embed_w  = (const float*)d_in[2];
    const float* w_ih     = (const float*)d_in[3];
    const float* w_hh     = (const float*)d_in[4];
    const float* b_ih     = (const float*)d_in[5];
    const float* b_hh     = (const float*)d_in[6];
    const float* key_w    = (const float*)d_in[7];
    const float* key_b    = (const float*)d_in[8];
    const float* val_w    = (const float*)d_in[9];
    const float* val_b    = (const float*)d_in[10];
    const float* query_w  = (const float*)d_in[11];
    const float* query_b  = (const float*)d_in[12];
    const float* head_w   = (const float*)d_in[13];
    const float* head_b   = (const float*)d_in[14];

    char* ws = (char*)d_ws;
    unsigned* kT2  = (unsigned*)(ws + WS_KT);
    unsigned* vT2  = (unsigned*)(ws + WS_V);
    float4*   G4   = (float4*)  (ws + WS_G4);
    unsigned* WPhh2 = (unsigned*)(ws + WS_WPHH);
    unsigned* WR2p  = (unsigned*)(ws + WS_WR);
    float4*   KQP   = (float4*)  (ws + WS_KQP);
    float4*   VWP   = (float4*)  (ws + WS_VWP);
    float*    KQf   = (float*)   (ws + WS_KQF);
    float*    bqv   = (float*)   (ws + WS_BQ);
    float*    kqv   = (float*)   (ws + WS_KQV);
    float*    c0p   = (float*)   (ws + WS_C0);
    float*    cB    = (float*)   (ws + WS_CB);

    (void)hipFuncSetAttribute((const void*)recurrent_main,
                              hipFuncAttributeMaxDynamicSharedMemorySize,
                              (int)SMEM_BYTES);

    pack_weights<<<64, 256, 0, stream>>>(w_ih, w_hh, val_w, WPhh2, WR2p, VWP);
    fold_kq<<<64, 64, 0, stream>>>(key_w, query_w, key_b, query_b,
                                   KQf, bqv, kqv, c0p);
    pack_kq<<<4, 256, 0, stream>>>(KQf, KQP);
    build_G<<<64, 64, 0, stream>>>(embed_w, w_ih, b_ih, G4);
    compute_kv<<<(B_*M_)/4, 256, 0, stream>>>(memory, bqv, val_b, KQP, VWP,
                                              kqv, c0p, kT2, vT2, cB);
    recurrent_main<<<B_, 64, SMEM_BYTES, stream>>>(seq, b_hh, head_w, head_b,
                                                   kT2, vT2, G4, WPhh2, WR2p, cB,
                                                   (float*)d_out);
}

// Round 11
// 1266.695 us; speedup vs baseline: 1.1418x; 1.1418x over previous
//
#include <hip/hip_runtime.h>
#include <hip/hip_fp16.h>

// FixedFreqModel: B=512, L=2048, M=256, H=64, VOCAB=64, READ_FREQ=16.
// R23 = R21 (1102us steady, best) + ONE edit: p broadcast via readlane.
//  - R22 post-mortem: kT-in-regs regressed (VGPR 196 proves residency; the
//    cost is AGPR-operand moves + regalloc squeeze -- same law as R13).
//    kT stays in LDS. Reverted wholesale.
//  - NEW: softmax's p never touches LDS. Each lane keeps its two packed
//    p-words (ppu0=pair mp=2j, ppu1=pair mp=2j+1); the v-loop fetches them
//    with 4 compile-time v_readlanes per iteration (the proven W_hh/WR
//    consumer pattern). Removes the ds_write+lgkmcnt round-trip (~120cy
//    serial), 32 broadcast ds_read_b128/chunk (halves LDS-pipe pressure
//    contending with vv reads), and the p barrier; the 6-shfl sum-reduce
//    now overlaps the v-loop (inv consumed only at the end). Bit-exact.
// Everything else byte-identical to R21: KQ-fold scores (kT in LDS),
// v-loop 4-acc, R-matvec, late-add G, 4-group GRU + cndmask tokens,
// W_hh + WR register-resident, no pins.

#define B_ 512
#define L_ 2048
#define M_ 256
#define H_ 64
#define C_ 128
#define F_ 16

typedef float v2f __attribute__((ext_vector_type(2)));
typedef _Float16 h2v __attribute__((ext_vector_type(2)));

#if __has_builtin(__builtin_amdgcn_fdot2)
__device__ __forceinline__ float FDOT2(h2v a, h2v b, float c) {
    return __builtin_amdgcn_fdot2(a, b, c, false);
}
#else
__device__ __forceinline__ float FDOT2(h2v a, h2v b, float c) {
    return c + (float)a[0]*(float)b[0] + (float)a[1]*(float)b[1];
}
#endif

__device__ __forceinline__ h2v bch(unsigned u) { return __builtin_bit_cast(h2v, u); }
__device__ __forceinline__ unsigned rl_u(unsigned v, int lane) {
    return (unsigned)__builtin_amdgcn_readlane((int)v, lane);
}
__device__ __forceinline__ float rl(float v, int lane) {
    return __int_as_float(__builtin_amdgcn_readlane(__float_as_int(v), lane));
}
__device__ __forceinline__ unsigned pkrtz(float a, float b) {
    auto r = __builtin_amdgcn_cvt_pkrtz(a, b);     // __fp16 ext_vector(2)
    return __builtin_bit_cast(unsigned, r);
}
__device__ __forceinline__ float dot4(float4 a, float4 b) {
    return a.x*b.x + a.y*b.y + a.z*b.z + a.w*b.w;
}
__device__ __forceinline__ float fast_rcp(float x) { return __builtin_amdgcn_rcpf(x); }
__device__ __forceinline__ float sigm(float x) { return fast_rcp(1.f + __expf(-x)); }
__device__ __forceinline__ float tanh_f(float x) {
    float e2 = __expf(-2.f * fabsf(x));
    return copysignf((1.f - e2) * fast_rcp(1.f + e2), x);
}
__device__ __forceinline__ unsigned h2rn(float a, float b) {
    __half2 h = __floats2half2_rn(a, b);
    return __builtin_bit_cast(unsigned, h);
}

// workspace offsets (bytes)
#define WS_KT    0u            // K'T2: 512 * 8192 u32 = 16 MB  [b][hh2][m]
#define WS_V     16777216u     // vT2: 512 * 8192 u32 = 16 MB  [b][o][mp]
#define WS_G     33554432u     // 64*192 fp32 = 48 KB
#define WS_WPHH  33603584u     // 6144 u32 = 24 KB  [(k2*3+g)*64+j]
#define WS_WR    33628160u     // 6144 u32 = 24 KB
#define WS_KQP   33652736u     // 1024 float4 = 16 KB (folded K.Q, packed)
#define WS_VWP   33669120u     // 16 KB
#define WS_KQF   33685504u     // 4096 fp32 = 16 KB (KQ scalar, pre-pack)
#define WS_BQ    33701888u     // 64 fp32 (bq = kb.Wq)
#define WS_KQV   33702144u     // 64 fp32 (kq = Kw^T qb)
#define WS_C0    33702400u     // 1 fp32 (c0 = kb.qb), padded
#define WS_CB    33702656u     // 512*256 fp32 = 512 KB (c[b][m])

// dynamic LDS layout (bytes)
#define S_KT   0u        // 32768 : K'T2 u32 [hh2=32][m=256]
#define S_V    32768u    // 33792 : vP u32 [o=64][132] (128 mp-pairs + 4 pad)
#define SMEM_BYTES 66560u

// ---------------- pack weights -----------------------------------------------
__global__ void pack_weights(const float* __restrict__ w_ih,
                             const float* __restrict__ w_hh,
                             const float* __restrict__ vw,
                             unsigned* __restrict__ WPhh2,
                             unsigned* __restrict__ WR2p,
                             float4* __restrict__ VWP)
{
    int idx = blockIdx.x * 256 + threadIdx.x;
    if (idx < 6144) {                        // WPhh2[(k2*3+g)*64+j]
        int j = idx & 63, t = idx >> 6, g = t % 3, k2 = t / 3;
        const float* s = w_hh + (g*64 + j)*64 + 2*k2;
        WPhh2[idx] = h2rn(s[0], s[1]);
    } else if (idx < 12288) {                // WR2p: retrieved half of w_ih
        int i = idx - 6144;
        int j = i & 63, t = i >> 6, g = t % 3, k2 = t / 3;
        const float* s = w_ih + (g*64 + j)*128 + 64 + 2*k2;
        WR2p[i] = h2rn(s[0], s[1]);
    } else if (idx < 13312) {                // VWP
        int i = idx - 12288;
        int j = i & 63, k4 = i >> 6;
        const float* s = vw + j*64 + 4*k4;
        VWP[i] = make_float4(s[0], s[1], s[2], s[3]);
    }
}

// ------ fold_kq: KQ[d][j] = sum_t Kw[t][d]*Wq[t][j]; bq, kq, c0 --------------
__global__ __launch_bounds__(64) void fold_kq(const float* __restrict__ kw,
                                              const float* __restrict__ qw,
                                              const float* __restrict__ kb,
                                              const float* __restrict__ qb,
                                              float* __restrict__ KQf,
                                              float* __restrict__ bqv,
                                              float* __restrict__ kqv,
                                              float* __restrict__ c0p)
{
    int d = blockIdx.x, j = threadIdx.x;
    __shared__ float kcol[64], kbs[64], qbs[64];
    kcol[j] = kw[j*64 + d];
    kbs[j]  = kb[j];
    qbs[j]  = qb[j];
    __syncthreads();
    float acc = 0.f, accq = 0.f;
    for (int t = 0; t < 64; ++t) {
        float kc = kcol[t];
        acc  += kc * qw[t*64 + j];
        accq += kc * qbs[t];
    }
    KQf[d*64 + j] = acc;
    if (j == 0) kqv[d] = accq;
    if (d == 0) {
        float vb = 0.f;
        for (int t = 0; t < 64; ++t) vb += kbs[t] * qw[t*64 + j];
        bqv[j] = vb;
        if (j == 0) {
            float c0 = 0.f;
            for (int t = 0; t < 64; ++t) c0 += kbs[t] * qbs[t];
            *c0p = c0;
        }
    }
}

// ------ pack_kq: KQP[k4*64+o] = (KQ[4k4+0..3][o]) for dot4 -------------------
__global__ __launch_bounds__(256) void pack_kq(const float* __restrict__ KQf,
                                               float4* __restrict__ KQP)
{
    int i = blockIdx.x * 256 + threadIdx.x;
    if (i < 1024) {
        int o = i & 63, k4 = i >> 6;
        KQP[i] = make_float4(KQf[(4*k4+0)*64 + o], KQf[(4*k4+1)*64 + o],
                             KQf[(4*k4+2)*64 + o], KQf[(4*k4+3)*64 + o]);
    }
}

// ---------------- G[v][o] = sum_k embed[v][k]*w_ih[o][k] + b_ih[o] ----------
__global__ __launch_bounds__(64) void build_G(const float* __restrict__ embed_w,
                                              const float* __restrict__ w_ih,
                                              const float* __restrict__ b_ih,
                                              float* __restrict__ G)
{
    int v = blockIdx.x, j = threadIdx.x;
    __shared__ float e_s[64];
    e_s[j] = embed_w[v*64 + j];
    __syncthreads();
    float a0 = b_ih[j], a1 = b_ih[64 + j], a2 = b_ih[128 + j];
    for (int k = 0; k < 64; ++k) {
        float e = e_s[k];
        a0 += e * w_ih[j*128 + k];
        a1 += e * w_ih[(64 + j)*128 + k];
        a2 += e * w_ih[(128 + j)*128 + k];
    }
    G[v*192 + j]       = a0;
    G[v*192 + 64 + j]  = a1;
    G[v*192 + 128 + j] = a2;
}

// ------- k/v precompute: K' (folded) pairs; v m-pair-transposed; c[b][m] -----
__global__ __launch_bounds__(256) void compute_kv(const float* __restrict__ memory,
                                                  const float* __restrict__ bqv,
                                                  const float* __restrict__ val_b,
                                                  const float4* __restrict__ KQP,
                                                  const float4* __restrict__ VWP,
                                                  const float* __restrict__ kqv,
                                                  const float* __restrict__ c0p,
                                                  unsigned* __restrict__ kT2,
                                                  unsigned* __restrict__ vT2,
                                                  float* __restrict__ cB)
{
    int wid = threadIdx.x >> 6;
    int o   = threadIdx.x & 63;
    int row = blockIdx.x * 4 + wid;          // row = b*256 + m
    int b = row >> 8, m = row & 255;
    __shared__ __align__(16) float mem_s[4][64];
    __shared__ float avs[4][64];
    mem_s[wid][o] = memory[(size_t)row * 64 + o];
    __syncthreads();
    float ak = bqv[o], av = val_b[o], ac = *c0p;
    const float4* m4  = (const float4*)mem_s[wid];
    const float4* kq4 = (const float4*)kqv;
#pragma unroll
    for (int k4 = 0; k4 < 16; ++k4) {
        float4 mm = m4[k4];
        ak += dot4(mm, KQP[k4*64 + o]);
        av += dot4(mm, VWP[k4*64 + o]);
        ac += dot4(mm, kq4[k4]);
    }
    float nb = __shfl_xor(ak, 1);            // K'[o^1][m]
    if ((o & 1) == 0)                        // pair (K'[o][m], K'[o+1][m])
        kT2[((size_t)b*32 + (o >> 1))*256 + m] = h2rn(ak, nb);
    avs[wid][o] = av;
    if (o == 0) cB[row] = ac;
    __syncthreads();
    if ((wid & 1) == 0) {                    // pair (v[m][o], v[m+1][o]), m even
        vT2[((size_t)b*64 + o)*128 + (m >> 1)] = h2rn(avs[wid][o], avs[wid+1][o]);
    }
}

// one GRU step: h broadcast as half2 via readlane; dot2 matvec; no LDS.
// G values (cg0/cg1) consumed at the TAIL so their load latency hides
// under the ~256cy matvec (fp32 reassociation only).
#define GRU_STEP(cg0, cg1, cg2) do {                                        \
    float gr = RrB, gz = RzB, gn = bhn;                                     \
    _Pragma("unroll")                                                       \
    for (int kp = 0; kp < 32; ++kp) {                                       \
        h2v hhp = bch(rl_u(hpu, 2*kp));                                     \
        gr = FDOT2(hhp, wr2[kp], gr);                                       \
        gz = FDOT2(hhp, wz2[kp], gz);                                       \
        gn = FDOT2(hhp, wn2[kp], gn);                                       \
    }                                                                       \
    float r_ = sigm(gr + (cg0));                                            \
    float z_ = sigm(gz + (cg1));                                            \
    float n_ = tanh_f(((cg2) + Rn) + r_ * gn);                              \
    h = fmaf(z_, h - n_, n_);                                               \
    float hx_ = __shfl_xor(h, 1);                                           \
    hpu = pkrtz(h, hx_);                                                    \
} while (0)

// ---------------- main recurrent kernel: 1 wave per batch element ------------
__global__ __launch_bounds__(64, 1) void recurrent_main(
    const int*   __restrict__ seq,
    const float* __restrict__ b_hh,
    const float* __restrict__ head_w,
    const float* __restrict__ head_b,
    const unsigned* __restrict__ kT2g,
    const unsigned* __restrict__ vT2g,
    const float* __restrict__ G,
    const unsigned* __restrict__ WPhh2,
    const unsigned* __restrict__ WR2p,
    const float* __restrict__ cB,
    float* __restrict__ out)
{
    const int b = blockIdx.x;
    const int j = threadIdx.x;

    extern __shared__ __align__(16) char smem[];
    const uint4* kT2_lds = (const uint4*)(smem + S_KT);  // [hh2*64 + j]: 4 m-pairs

    // ---- stage K'T2, vT2 (repad 128->132 u32 rows) into LDS once ----
    {
        const uint4* kTg = (const uint4*)(kT2g + (size_t)b * 8192);
        uint4* kTls = (uint4*)(smem + S_KT);
#pragma unroll
        for (int i = 0; i < 32; ++i) kTls[i*64 + j] = kTg[i*64 + j];
        const uint4* vg4 = (const uint4*)(vT2g + (size_t)b * 8192);
        uint4* vls4 = (uint4*)(smem + S_V);
#pragma unroll
        for (int i = 0; i < 32; ++i) {
            int t = i*64 + j;                 // global quad: o = t>>5, q = t&31
            vls4[(t >> 5)*33 + (t & 31)] = vg4[t];
        }
    }

    // ---- W_hh in registers as half2: 96 words (compiler parks in AGPRs) ----
    h2v wr2[32], wz2[32], wn2[32];
#pragma unroll
    for (int k2 = 0; k2 < 32; ++k2) {
        wr2[k2] = bch(WPhh2[(k2*3 + 0)*64 + j]);
        wz2[k2] = bch(WPhh2[(k2*3 + 1)*64 + j]);
        wn2[k2] = bch(WPhh2[(k2*3 + 2)*64 + j]);
    }
    // ---- WR (retrieved-half of w_ih) likewise: 96 words, loaded ONCE ----
    h2v rr2[32], rz2[32], rn2[32];
#pragma unroll
    for (int k2 = 0; k2 < 32; ++k2) {
        rr2[k2] = bch(WR2p[(k2*3 + 0)*64 + j]);
        rz2[k2] = bch(WR2p[(k2*3 + 1)*64 + j]);
        rn2[k2] = bch(WR2p[(k2*3 + 2)*64 + j]);
    }

    float h = 0.f;                       // lane j owns h[j]; never leaves regs
    unsigned hpu = 0u;                   // packed (h[2t], h[2t+1]) fp16 pair
    const float bhr = b_hh[j], bhz = b_hh[64 + j], bhn = b_hh[128 + j];
    // scores bias: c[b][m] for lane's m = 4j..4j+3 (fp32, in regs all session)
    const float4 cc = *(const float4*)(cB + (size_t)b*256 + 4*j);

    const int* seqb = seq + (size_t)b * L_;
    const uint4* vrow = (const uint4*)(smem + S_V) + j*33;   // lane's o-row
    __builtin_amdgcn_wave_barrier();

    for (int c = 0; c < C_; ++c) {
        const int c16 = c * F_;

        // ---- token hoist: all 4 group int4s issued at chunk top ----
        const int4 pA = *(const int4*)(seqb + c16);
        const int4 pB = *(const int4*)(seqb + c16 + 4);
        const int4 pC = *(const int4*)(seqb + c16 + 8);
        const int4 pD = *(const int4*)(seqb + c16 + 12);

        // ---- scores directly from h pairs (q folded into K'): lane j owns
        //      m = 4j..4j+3; s init = c[m] ----
        float s0 = cc.x, s1 = cc.y, s2 = cc.z, s3 = cc.w;
#pragma unroll 8
        for (int t = 0; t < 32; ++t) {
            h2v qq = bch(rl_u(hpu, 2*t));
            uint4 kk = kT2_lds[t*64 + j];
            s0 = FDOT2(bch(kk.x), qq, s0);
            s1 = FDOT2(bch(kk.y), qq, s1);
            s2 = FDOT2(bch(kk.z), qq, s2);
            s3 = FDOT2(bch(kk.w), qq, s3);
        }
        const float scale = 0.125f;
        // softmax, no max-sub (|s| small), rcp not div
        float4 p;
        p.x = __expf(s0*scale); p.y = __expf(s1*scale);
        p.z = __expf(s2*scale); p.w = __expf(s3*scale);
        // p stays in registers as packed fp16 pairs; v-loop fetches via
        // readlane (no LDS round-trip). ppu0 = pair mp=2j, ppu1 = mp=2j+1.
        const unsigned ppu0 = pkrtz(p.x, p.y);
        const unsigned ppu1 = pkrtz(p.z, p.w);
        float sum = (p.x + p.y) + (p.z + p.w);
#pragma unroll
        for (int o = 32; o > 0; o >>= 1) sum += __shfl_xor(sum, o);
        float inv = fast_rcp(sum);    // consumed only after the v-loop:
                                      // the reduce overlaps the dot2 stream

        // ---- retrieved: lane j owns ret[j]; 4 accs; p via readlane ----
        float r0 = 0.f, r1 = 0.f, r2 = 0.f, r3 = 0.f;
#pragma unroll 8
        for (int qd = 0; qd < 32; ++qd) {
            uint4 vv = vrow[qd];          // pairs mp = 4qd..4qd+3 for o=j
            unsigned px = rl_u(ppu0, 2*qd);      // pair mp=4qd
            unsigned py = rl_u(ppu1, 2*qd);      // pair mp=4qd+1
            unsigned pz = rl_u(ppu0, 2*qd + 1);  // pair mp=4qd+2
            unsigned pw = rl_u(ppu1, 2*qd + 1);  // pair mp=4qd+3
            r0 = FDOT2(bch(px), bch(vv.x), r0);
            r1 = FDOT2(bch(py), bch(vv.y), r1);
            r2 = FDOT2(bch(pz), bch(vv.z), r2);
            r3 = FDOT2(bch(pw), bch(vv.w), r3);
        }
        float ret = ((r0 + r1) + (r2 + r3)) * inv;

        // ---- R matvec: ret packed like h (pairs via shfl); WR in regs ----
        float rx = __shfl_xor(ret, 1);
        unsigned rpu = pkrtz(ret, rx);
        float Rr = 0.f, Rz = 0.f, Rn = 0.f;
#pragma unroll
        for (int k2 = 0; k2 < 32; ++k2) {
            h2v rr = bch(rl_u(rpu, 2*k2));
            Rr = FDOT2(rr, rr2[k2], Rr);
            Rz = FDOT2(rr, rz2[k2], Rz);
            Rn = FDOT2(rr, rn2[k2], Rn);
        }
        const float RrB = Rr + bhr, RzB = Rz + bhz;

        // ---- 16 GRU steps: 4 dynamic groups x 4 unrolled (I-cache OK).
        //      Tokens from hoisted regs via cndmask; G loads issued at group
        //      top, consumed at step tails (late-add). ----
#pragma unroll 1
        for (int g = 0; g < 4; ++g) {
            const bool gb1 = (g & 1), gb2 = (g & 2);
            int4 tlo, thi, tg;
            tlo.x = gb1 ? pB.x : pA.x; tlo.y = gb1 ? pB.y : pA.y;
            tlo.z = gb1 ? pB.z : pA.z; tlo.w = gb1 ? pB.w : pA.w;
            thi.x = gb1 ? pD.x : pC.x; thi.y = gb1 ? pD.y : pC.y;
            thi.z = gb1 ? pD.z : pC.z; thi.w = gb1 ? pD.w : pC.w;
            tg.x = gb2 ? thi.x : tlo.x; tg.y = gb2 ? thi.y : tlo.y;
            tg.z = gb2 ? thi.z : tlo.z; tg.w = gb2 ? thi.w : tlo.w;
            const float* GA = G + tg.x*192;
            const float* GB = G + tg.y*192;
            const float* GC = G + tg.z*192;
            const float* GD = G + tg.w*192;
            float gA0 = GA[j], gA1 = GA[64+j], gA2 = GA[128+j];
            float gB0 = GB[j], gB1 = GB[64+j], gB2 = GB[128+j];
            float gC0 = GC[j], gC1 = GC[64+j], gC2 = GC[128+j];
            float gD0 = GD[j], gD1 = GD[64+j], gD2 = GD[128+j];

            GRU_STEP(gA0, gA1, gA2);
            GRU_STEP(gB0, gB1, gB2);
            GRU_STEP(gC0, gC1, gC2);
            GRU_STEP(gD0, gD1, gD2);
        }
    }

    // ---- head: out[b][j] = head_b[j] + sum_k h[k]*head_w[j][k] (fp32) ----
    float o = head_b[j];
#pragma unroll
    for (int k4 = 0; k4 < 16; ++k4) {
        float h0 = rl(h, 4*k4+0), h1 = rl(h, 4*k4+1);
        float h2 = rl(h, 4*k4+2), h3 = rl(h, 4*k4+3);
        const float* hw = head_w + j*64 + 4*k4;
        o += h0*hw[0] + h1*hw[1] + h2*hw[2] + h3*hw[3];
    }
    out[(size_t)b*64 + j] = o;
}

extern "C" void kernel_launch(void* const* d_in, const int* in_sizes, int n_in,
                              void* d_out, int out_size, void* d_ws, size_t ws_size,
                              hipStream_t stream) {
    const int*   seq      = (const int*)  d_in[0];
    const float* memory   = (const float*)d_in[1];
    const float* embed_w  = (const float*)d_in[2];
    const float* w_ih     = (const float*)d_in[3];
    const float* w_hh     = (const float*)d_in[4];
    const float* b_ih     = (const float*)d_in[5];
    const float* b_hh     = (const float*)d_in[6];
    const float* key_w    = (const float*)d_in[7];
    const float* key_b    = (const float*)d_in[8];
    const float* val_w    = (const float*)d_in[9];
    const float* val_b    = (const float*)d_in[10];
    const float* query_w  = (const float*)d_in[11];
    const float* query_b  = (const float*)d_in[12];
    const float* head_w   = (const float*)d_in[13];
    const float* head_b   = (const float*)d_in[14];

    char* ws = (char*)d_ws;
    unsigned* kT2  = (unsigned*)(ws + WS_KT);
    unsigned* vT2  = (unsigned*)(ws + WS_V);
    float*    G    = (float*)   (ws + WS_G);
    unsigned* WPhh2 = (unsigned*)(ws + WS_WPHH);
    unsigned* WR2p  = (unsigned*)(ws + WS_WR);
    float4*   KQP   = (float4*)  (ws + WS_KQP);
    float4*   VWP   = (float4*)  (ws + WS_VWP);
    float*    KQf   = (float*)   (ws + WS_KQF);
    float*    bqv   = (float*)   (ws + WS_BQ);
    float*    kqv   = (float*)   (ws + WS_KQV);
    float*    c0p   = (float*)   (ws + WS_C0);
    float*    cB    = (float*)   (ws + WS_CB);

    (void)hipFuncSetAttribute((const void*)recurrent_main,
                              hipFuncAttributeMaxDynamicSharedMemorySize,
                              (int)SMEM_BYTES);

    pack_weights<<<64, 256, 0, stream>>>(w_ih, w_hh, val_w, WPhh2, WR2p, VWP);
    fold_kq<<<64, 64, 0, stream>>>(key_w, query_w, key_b, query_b,
                                   KQf, bqv, kqv, c0p);
    pack_kq<<<4, 256, 0, stream>>>(KQf, KQP);
    build_G<<<64, 64, 0, stream>>>(embed_w, w_ih, b_ih, G);
    compute_kv<<<(B_*M_)/4, 256, 0, stream>>>(memory, bqv, val_b, KQP, VWP,
                                              kqv, c0p, kT2, vT2, cB);
    recurrent_main<<<B_, 64, SMEM_BYTES, stream>>>(seq, b_hh, head_w, head_b,
                                                   kT2, vT2, G, WPhh2, WR2p, cB,
                                                   (float*)d_out);
}